// Round 9
// baseline (759.675 us; speedup 1.0000x reference)
//
#include <hip/hip_runtime.h>
#include <cstdint>

typedef __bf16 bf16;
typedef __bf16 bf16x8 __attribute__((ext_vector_type(8)));
typedef float f32x4 __attribute__((ext_vector_type(4)));

__device__ __forceinline__ void load_lds16(const void* g, void* l) {
  __builtin_amdgcn_global_load_lds(
      (const __attribute__((address_space(1))) void*)g,
      (__attribute__((address_space(3))) void*)l, 16, 0, 0);
}

__device__ __forceinline__ unsigned short bf16_bits(float f) {
  return __builtin_bit_cast(unsigned short, (bf16)f);
}
__device__ __forceinline__ float bf_lo(unsigned u) {
  return __uint_as_float(u << 16);
}
__device__ __forceinline__ float bf_hi(unsigned u) {
  return __uint_as_float(u & 0xffff0000u);
}

// ---------------------------------------------------------------------------
// CSR-by-dst build
// ---------------------------------------------------------------------------
__global__ void hist_kernel(const int* __restrict__ ei, int E, int N,
                            int* __restrict__ counts) {
  const int total = E + N;
  for (int i = blockIdx.x * blockDim.x + threadIdx.x; i < total;
       i += gridDim.x * blockDim.x) {
    const int d = (i < E) ? ei[E + i] : (i - E);
    atomicAdd(&counts[d], 1);
  }
}

// 3-phase parallel exclusive scan over counts[N] (256 blocks).
__global__ void scan_reduce(const int* __restrict__ counts,
                            int* __restrict__ bsum, int N) {
  __shared__ int red[256];
  const int chunk = (N + 255) / 256;
  const int lo = blockIdx.x * chunk;
  const int hi = min(lo + chunk, N);
  int s = 0;
  for (int i = lo + threadIdx.x; i < hi; i += 256) s += counts[i];
  red[threadIdx.x] = s;
  __syncthreads();
  for (int off = 128; off; off >>= 1) {
    if (threadIdx.x < off) red[threadIdx.x] += red[threadIdx.x + off];
    __syncthreads();
  }
  if (threadIdx.x == 0) bsum[blockIdx.x] = red[0];
}

__global__ void scan_bsum(int* __restrict__ bsum, int* __restrict__ row_ptr,
                          int N) {
  __shared__ int tmp[256];
  const int tid = threadIdx.x;
  const int v = bsum[tid];
  tmp[tid] = v;
  __syncthreads();
  for (int off = 1; off < 256; off <<= 1) {
    const int t = (tid >= off) ? tmp[tid - off] : 0;
    __syncthreads();
    tmp[tid] += t;
    __syncthreads();
  }
  bsum[tid] = tmp[tid] - v;  // exclusive block offsets
  if (tid == 255) row_ptr[N] = tmp[255];
}

__global__ void scan_write(const int* __restrict__ counts,
                           const int* __restrict__ boff,
                           int* __restrict__ row_ptr, int* __restrict__ cursor,
                           int N) {
  __shared__ int tmp[256];
  const int chunk = (N + 255) / 256;
  const int lo = blockIdx.x * chunk;
  const int hi = min(lo + chunk, N);
  int carry = boff[blockIdx.x];
  for (int base = lo; base < hi; base += 256) {
    const int i = base + threadIdx.x;
    const int v = (i < hi) ? counts[i] : 0;
    tmp[threadIdx.x] = v;
    __syncthreads();
    for (int off = 1; off < 256; off <<= 1) {
      const int t = (threadIdx.x >= off) ? tmp[threadIdx.x - off] : 0;
      __syncthreads();
      tmp[threadIdx.x] += t;
      __syncthreads();
    }
    if (i < hi) {
      const int excl = carry + tmp[threadIdx.x] - v;
      row_ptr[i] = excl;
      cursor[i] = excl;
    }
    carry += tmp[255];
    __syncthreads();
  }
}

// scatter: csr_src[pos] = src (random write), pos_of[i] = pos (coalesced).
__global__ void scatter_kernel(const int* __restrict__ ei, int E, int N,
                               int* __restrict__ cursor,
                               int* __restrict__ csr_src,
                               int* __restrict__ pos_of) {
  const int total = E + N;
  for (int i = blockIdx.x * blockDim.x + threadIdx.x; i < total;
       i += gridDim.x * blockDim.x) {
    int s, d;
    if (i < E) { s = ei[i]; d = ei[E + i]; } else { s = d = i - E; }
    const int pos = atomicAdd(&cursor[d], 1);
    csr_src[pos] = s;
    pos_of[i] = pos;
  }
}

// ---------------------------------------------------------------------------
// small helpers
// ---------------------------------------------------------------------------
__global__ void mmse_kernel(const float* __restrict__ score,
                            const float* __restrict__ W,
                            const float* __restrict__ b,
                            float* __restrict__ out, int D) {
  const int i = threadIdx.x;
  if (i < D) out[i] = score[0] * W[i] + b[i];
}

__global__ void wt_kernel(const float* __restrict__ Wl,
                          const float* __restrict__ Wr,
                          bf16* __restrict__ Wt, int K) {
  const int idx = blockIdx.x * blockDim.x + threadIdx.x;
  if (idx >= 256 * K) return;
  const int col = idx & 255;
  const int k = idx >> 8;
  const float v = (col < 128) ? Wl[k * 128 + col] : Wr[k * 128 + (col - 128)];
  Wt[(size_t)col * K + k] = (bf16)v;
}

// ---------------------------------------------------------------------------
// MFMA GEMM: [xl | xr] = A[M][K] @ Wt^T   (Wt is [256][K] bf16, col-major W)
// BM=128, BN=256, BK=32; 512 threads = 8 waves (2x4), 64x64 per wave.
// ---------------------------------------------------------------------------
template <bool AF32>
__global__ __launch_bounds__(512) void gemm_mfma(
    const void* __restrict__ Ap, const bf16* __restrict__ Wt,
    bf16* __restrict__ xl, bf16* __restrict__ xr, int M, int K) {
  __shared__ __align__(16) bf16 Alds[128 * 32];
  __shared__ __align__(16) bf16 Blds[256 * 32];

  const int tid = threadIdx.x;
  const int w = tid >> 6, lane = tid & 63;
  const int wr = w >> 2, wc = w & 3;
  const int row0 = blockIdx.x * 128;

  const int s_row = tid >> 2;
  const int s_k = (tid & 3) * 8;
  const int a_row = min(row0 + s_row, M - 1);
  bf16* a_dst = Alds + tid * 8;

  const int b_col0 = w * 32 + (lane >> 2);
  const bf16* b_src0 = Wt + (size_t)b_col0 * K + (lane & 3) * 8;
  const bf16* b_src1 = Wt + (size_t)(b_col0 + 16) * K + (lane & 3) * 8;
  bf16* b_dst0 = Blds + w * 1024 + lane * 8;
  bf16* b_dst1 = b_dst0 + 512;

  const int a_f0 = (wr * 64 + (lane & 15)) * 32 + (lane >> 4) * 8;
  const int b_f0 = (wc * 64 + (lane & 15)) * 32 + (lane >> 4) * 8;

  f32x4 acc[4][4] = {};

  for (int k0 = 0; k0 < K; k0 += 32) {
    bf16x8 av;
    if (AF32) {
      const float* A = (const float*)Ap;
      const float4 f0 = *(const float4*)&A[(size_t)a_row * K + k0 + s_k];
      const float4 f1 = *(const float4*)&A[(size_t)a_row * K + k0 + s_k + 4];
      av[0] = (bf16)f0.x; av[1] = (bf16)f0.y; av[2] = (bf16)f0.z; av[3] = (bf16)f0.w;
      av[4] = (bf16)f1.x; av[5] = (bf16)f1.y; av[6] = (bf16)f1.z; av[7] = (bf16)f1.w;
    } else {
      av = *(const bf16x8*)((const bf16*)Ap + (size_t)a_row * K + k0 + s_k);
    }
    __syncthreads();
    *(bf16x8*)a_dst = av;
    load_lds16(b_src0 + k0, b_dst0);
    load_lds16(b_src1 + k0, b_dst1);
    __syncthreads();

    bf16x8 af[4], bfr[4];
#pragma unroll
    for (int m = 0; m < 4; ++m) af[m] = *(const bf16x8*)(Alds + a_f0 + m * 512);
#pragma unroll
    for (int n = 0; n < 4; ++n) bfr[n] = *(const bf16x8*)(Blds + b_f0 + n * 512);
#pragma unroll
    for (int m = 0; m < 4; ++m)
#pragma unroll
      for (int n = 0; n < 4; ++n)
        acc[m][n] = __builtin_amdgcn_mfma_f32_16x16x32_bf16(af[m], bfr[n],
                                                            acc[m][n], 0, 0, 0);
  }

#pragma unroll
  for (int m = 0; m < 4; ++m) {
    const int rbase = row0 + wr * 64 + m * 16 + (lane >> 4) * 4;
#pragma unroll
    for (int n = 0; n < 4; ++n) {
      const int c = wc * 64 + n * 16 + (lane & 15);
      bf16* dst = (c < 128) ? xl : xr;
      const int cc = c & 127;
#pragma unroll
      for (int j = 0; j < 4; ++j) {
        const int r = rbase + j;
        if (r < M) dst[(size_t)r * 128 + cc] = (bf16)acc[m][n][j];
      }
    }
  }
}

// ---------------------------------------------------------------------------
// edge phase v6: back to v3's simple batched loop (best measured structure),
// + coalesced e_ws (CSR order, no eid in hot loop), minimal registers,
// __launch_bounds__(256,8) to pin 8 waves/SIMD (TLP hides gather latency).
// 2 nodes per wave (32-lane halves), 4 dims per lane, 8-edge batches.
// ---------------------------------------------------------------------------
__global__ __launch_bounds__(256, 8) void gat_edge(
    const bf16* __restrict__ xl, const bf16* __restrict__ xr,
    const int* __restrict__ row_ptr, const int* __restrict__ csr_src,
    const float* __restrict__ att, const float* __restrict__ bias,
    const float* __restrict__ extra,
    bf16* __restrict__ out_b,   // layer 1: attn1 (bf16) or null
    float* __restrict__ out_f,  // layer 2: out_feat (fp32) or null
    float* __restrict__ e_ws, float* __restrict__ m_ws,
    float* __restrict__ den_ws, int N) {
  const int wave = threadIdx.x >> 6;
  const int lane = threadIdx.x & 63;
  const int l5 = lane & 31;
  const int half = lane >> 5;
  const int node_raw = blockIdx.x * 8 + wave * 2 + half;
  const bool vnode = node_raw < N;
  const int node = vnode ? node_raw : N - 1;

  const int d0 = l5 * 4;
  const float4 attv = *(const float4*)&att[d0];
  const uint2 ur = *(const uint2*)&xr[(size_t)node * 128 + d0];
  const float r0 = bf_lo(ur.x), r1 = bf_hi(ur.x);
  const float r2 = bf_lo(ur.y), r3 = bf_hi(ur.y);

  float m = -1e30f, den = 0.f;
  float a0 = 0.f, a1 = 0.f, a2 = 0.f, a3 = 0.f;

  const int beg = vnode ? row_ptr[node] : 0;
  const int end = vnode ? row_ptr[node + 1] : 0;
  const int nbat = (end - beg + 7) >> 3;
  const int nloop = max(nbat, __shfl_xor(nbat, 32));

  for (int t = 0; t < nloop; ++t) {
    const int idx = beg + t * 8;

    // 8 independent idx->gather chains; compiler interleaves them.
    uint2 u[8];
#pragma unroll
    for (int j = 0; j < 8; ++j) {
      const int k = idx + j;
      const int s = csr_src[(k < end) ? k : beg];  // ephemeral index reg
      u[j] = *(const uint2*)&xl[(size_t)s * 128 + d0];
    }

    float p[8];
#pragma unroll
    for (int j = 0; j < 8; ++j) {
      float h0 = bf_lo(u[j].x) + r0;
      float h1 = bf_hi(u[j].x) + r1;
      float h2 = bf_lo(u[j].y) + r2;
      float h3 = bf_hi(u[j].y) + r3;
      h0 = fmaxf(h0, 0.2f * h0);  // LeakyReLU: max(h, 0.2h)
      h1 = fmaxf(h1, 0.2f * h1);
      h2 = fmaxf(h2, 0.2f * h2);
      h3 = fmaxf(h3, 0.2f * h3);
      p[j] = fmaf(h0, attv.x, fmaf(h1, attv.y, fmaf(h2, attv.z, h3 * attv.w)));
    }

    // reduce within each 32-lane half (offsets preserve the half bit)
#pragma unroll
    for (int off = 16; off; off >>= 1) {
#pragma unroll
      for (int j = 0; j < 8; ++j) p[j] += __shfl_xor(p[j], off);
    }

#pragma unroll
    for (int j = 0; j < 8; ++j)
      if (idx + j >= end) p[j] = -1e30f;  // masked: weight 0

    if (e_ws != nullptr && l5 == 0) {
#pragma unroll
      for (int j = 0; j < 8; ++j)
        if (idx + j < end) e_ws[idx + j] = p[j];  // CSR order: coalesced
    }

    const float bm = fmaxf(fmaxf(fmaxf(p[0], p[1]), fmaxf(p[2], p[3])),
                           fmaxf(fmaxf(p[4], p[5]), fmaxf(p[6], p[7])));
    if (bm > m) {
      const float f = __expf(m - bm);  // 0 on first batch
      den *= f;
      a0 *= f; a1 *= f; a2 *= f; a3 *= f;
      m = bm;
    }
#pragma unroll
    for (int j = 0; j < 8; ++j) {
      const float wgt = __expf(p[j] - m);
      den += wgt;
      a0 = fmaf(wgt, bf_lo(u[j].x), a0);
      a1 = fmaf(wgt, bf_hi(u[j].x), a1);
      a2 = fmaf(wgt, bf_lo(u[j].y), a2);
      a3 = fmaf(wgt, bf_hi(u[j].y), a3);
    }
  }

  if (!vnode) return;

  const float inv = 1.f / den;
  const float4 bv = *(const float4*)&bias[d0];
  float o0 = fmaf(a0, inv, bv.x);
  float o1 = fmaf(a1, inv, bv.y);
  float o2 = fmaf(a2, inv, bv.z);
  float o3 = fmaf(a3, inv, bv.w);
  if (extra != nullptr) {
    const float4 ev = *(const float4*)&extra[d0];
    o0 += ev.x; o1 += ev.y; o2 += ev.z; o3 += ev.w;
  }
  if (out_b != nullptr) {
    uint2 pk;
    pk.x = (unsigned)bf16_bits(o0) | ((unsigned)bf16_bits(o1) << 16);
    pk.y = (unsigned)bf16_bits(o2) | ((unsigned)bf16_bits(o3) << 16);
    *(uint2*)&out_b[(size_t)node * 128 + d0] = pk;
  }
  if (out_f != nullptr) {
    float4 ov; ov.x = o0; ov.y = o1; ov.z = o2; ov.w = o3;
    *(float4*)&out_f[(size_t)node * 128 + d0] = ov;
  }
  if (m_ws != nullptr && l5 == 0) {
    m_ws[node] = m;
    den_ws[node] = den;
  }
}

// alpha[i] = exp(e[pos_of[i]] - m[dst]) / den[dst]  (original edge order)
__global__ void alpha_kernel(const float* __restrict__ e_ws,
                             const float* __restrict__ m_ws,
                             const float* __restrict__ den_ws,
                             const int* __restrict__ ei,
                             const int* __restrict__ pos_of, int E, int N,
                             float* __restrict__ out_alpha) {
  const int i = blockIdx.x * blockDim.x + threadIdx.x;
  if (i >= E + N) return;
  const int d = (i < E) ? ei[E + i] : (i - E);
  const int pos = pos_of[i];
  out_alpha[i] = __expf(e_ws[pos] - m_ws[d]) / den_ws[d];
}

// ---------------------------------------------------------------------------
extern "C" void kernel_launch(void* const* d_in, const int* in_sizes, int n_in,
                              void* d_out, int out_size, void* d_ws,
                              size_t ws_size, hipStream_t stream) {
  const float* x          = (const float*)d_in[0];
  const int*   ei         = (const int*)d_in[1];
  const float* mmse_score = (const float*)d_in[2];
  const float* W_l1       = (const float*)d_in[3];
  const float* W_r1       = (const float*)d_in[4];
  const float* att1       = (const float*)d_in[5];
  const float* bias1      = (const float*)d_in[6];
  const float* W_l2       = (const float*)d_in[7];
  const float* W_r2       = (const float*)d_in[8];
  const float* att2       = (const float*)d_in[9];
  const float* bias2      = (const float*)d_in[10];
  const float* mmse_W     = (const float*)d_in[11];
  const float* mmse_b     = (const float*)d_in[12];

  const int D  = in_sizes[5];      // 128
  const int T  = in_sizes[3] / D;  // 512
  const int N  = in_sizes[0] / T;  // 50000
  const int E  = in_sizes[1] / 2;  // 800000
  const int ET = E + N;

  char* wptr = (char*)d_ws;
  auto alloc = [&](size_t bytes) {
    char* p = wptr;
    wptr += (bytes + 255) & ~(size_t)255;
    return p;
  };
  bf16* xl      = (bf16*)alloc((size_t)N * 128 * 2);
  bf16* xr      = (bf16*)alloc((size_t)N * 128 * 2);
  bf16* attn1   = (bf16*)alloc((size_t)N * 128 * 2);
  bf16* Wt1     = (bf16*)alloc((size_t)256 * T * 2);
  bf16* Wt2     = (bf16*)alloc((size_t)256 * D * 2);
  float* e_ws   = (float*)alloc((size_t)ET * 4);
  float* m_ws   = (float*)alloc((size_t)N * 4);
  float* den_ws = (float*)alloc((size_t)N * 4);
  float* mmse_vec = (float*)alloc(512);
  int* counts  = (int*)alloc((size_t)N * 4);
  int* row_ptr = (int*)alloc((size_t)(N + 1) * 4);
  int* cursor  = (int*)alloc((size_t)N * 4);
  int* bsum    = (int*)alloc(256 * 4);
  int* csr_src = (int*)alloc((size_t)ET * 4);
  int* pos_of  = (int*)alloc((size_t)ET * 4);

  float* out_feat  = (float*)d_out;             // N*128
  float* out_alpha = out_feat + (size_t)N * D;  // ET

  // 1. CSR by dst (parallel scan)
  hipMemsetAsync(counts, 0, (size_t)N * 4, stream);
  hist_kernel<<<2048, 256, 0, stream>>>(ei, E, N, counts);
  scan_reduce<<<256, 256, 0, stream>>>(counts, bsum, N);
  scan_bsum<<<1, 256, 0, stream>>>(bsum, row_ptr, N);
  scan_write<<<256, 256, 0, stream>>>(counts, bsum, row_ptr, cursor, N);
  scatter_kernel<<<2048, 256, 0, stream>>>(ei, E, N, cursor, csr_src, pos_of);

  // 2. weight prep + mmse embedding
  wt_kernel<<<(256 * T + 255) / 256, 256, 0, stream>>>(W_l1, W_r1, Wt1, T);
  wt_kernel<<<(256 * D + 255) / 256, 256, 0, stream>>>(W_l2, W_r2, Wt2, D);
  mmse_kernel<<<1, 128, 0, stream>>>(mmse_score, mmse_W, mmse_b, mmse_vec, D);

  // 3. layer-1 GEMM (fp32 A, converts inline) -> xl/xr bf16
  const int gblocks = (N + 127) / 128;
  gemm_mfma<true><<<gblocks, 512, 0, stream>>>(x, Wt1, xl, xr, N, T);

  // 4. layer-1 edge phase -> attn1 bf16, logits (CSR order) for alpha
  gat_edge<<<(N + 7) / 8, 256, 0, stream>>>(xl, xr, row_ptr, csr_src, att1,
                                            bias1, nullptr, attn1, nullptr,
                                            e_ws, m_ws, den_ws, N);

  // 5. alpha in original edge order
  alpha_kernel<<<(ET + 255) / 256, 256, 0, stream>>>(e_ws, m_ws, den_ws, ei,
                                                     pos_of, E, N, out_alpha);

  // 6. layer-2 GEMM (bf16 A = attn1) -> xl/xr reused
  gemm_mfma<false><<<gblocks, 512, 0, stream>>>(attn1, Wt2, xl, xr, N, D);

  // 7. layer-2 edge phase -> out_feat fp32 (+ mmse embedding)
  gat_edge<<<(N + 7) / 8, 256, 0, stream>>>(xl, xr, row_ptr, csr_src, att2,
                                            bias2, mmse_vec, nullptr, out_feat,
                                            nullptr, nullptr, nullptr, N);
}

// Round 10
// 425.649 us; speedup vs baseline: 1.7847x; 1.7847x over previous
//
#include <hip/hip_runtime.h>
#include <cstdint>

typedef __bf16 bf16;
typedef __bf16 bf16x8 __attribute__((ext_vector_type(8)));
typedef float f32x4 __attribute__((ext_vector_type(4)));

__device__ __forceinline__ void load_lds16(const void* g, void* l) {
  __builtin_amdgcn_global_load_lds(
      (const __attribute__((address_space(1))) void*)g,
      (__attribute__((address_space(3))) void*)l, 16, 0, 0);
}

__device__ __forceinline__ unsigned short bf16_bits(float f) {
  return __builtin_bit_cast(unsigned short, (bf16)f);
}
__device__ __forceinline__ float bf_lo(unsigned u) {
  return __uint_as_float(u << 16);
}
__device__ __forceinline__ float bf_hi(unsigned u) {
  return __uint_as_float(u & 0xffff0000u);
}

// ---------------------------------------------------------------------------
// CSR-by-dst build
// ---------------------------------------------------------------------------
__global__ void hist_kernel(const int* __restrict__ ei, int E, int N,
                            int* __restrict__ counts) {
  const int total = E + N;
  for (int i = blockIdx.x * blockDim.x + threadIdx.x; i < total;
       i += gridDim.x * blockDim.x) {
    const int d = (i < E) ? ei[E + i] : (i - E);
    atomicAdd(&counts[d], 1);
  }
}

// 3-phase parallel exclusive scan over counts[N] (256 blocks).
__global__ void scan_reduce(const int* __restrict__ counts,
                            int* __restrict__ bsum, int N) {
  __shared__ int red[256];
  const int chunk = (N + 255) / 256;
  const int lo = blockIdx.x * chunk;
  const int hi = min(lo + chunk, N);
  int s = 0;
  for (int i = lo + threadIdx.x; i < hi; i += 256) s += counts[i];
  red[threadIdx.x] = s;
  __syncthreads();
  for (int off = 128; off; off >>= 1) {
    if (threadIdx.x < off) red[threadIdx.x] += red[threadIdx.x + off];
    __syncthreads();
  }
  if (threadIdx.x == 0) bsum[blockIdx.x] = red[0];
}

__global__ void scan_bsum(int* __restrict__ bsum, int* __restrict__ row_ptr,
                          int N) {
  __shared__ int tmp[256];
  const int tid = threadIdx.x;
  const int v = bsum[tid];
  tmp[tid] = v;
  __syncthreads();
  for (int off = 1; off < 256; off <<= 1) {
    const int t = (tid >= off) ? tmp[tid - off] : 0;
    __syncthreads();
    tmp[tid] += t;
    __syncthreads();
  }
  bsum[tid] = tmp[tid] - v;  // exclusive block offsets
  if (tid == 255) row_ptr[N] = tmp[255];
}

__global__ void scan_write(const int* __restrict__ counts,
                           const int* __restrict__ boff,
                           int* __restrict__ row_ptr, int* __restrict__ cursor,
                           int N) {
  __shared__ int tmp[256];
  const int chunk = (N + 255) / 256;
  const int lo = blockIdx.x * chunk;
  const int hi = min(lo + chunk, N);
  int carry = boff[blockIdx.x];
  for (int base = lo; base < hi; base += 256) {
    const int i = base + threadIdx.x;
    const int v = (i < hi) ? counts[i] : 0;
    tmp[threadIdx.x] = v;
    __syncthreads();
    for (int off = 1; off < 256; off <<= 1) {
      const int t = (threadIdx.x >= off) ? tmp[threadIdx.x - off] : 0;
      __syncthreads();
      tmp[threadIdx.x] += t;
      __syncthreads();
    }
    if (i < hi) {
      const int excl = carry + tmp[threadIdx.x] - v;
      row_ptr[i] = excl;
      cursor[i] = excl;
    }
    carry += tmp[255];
    __syncthreads();
  }
}

// scatter: csr_src[pos] = src (random write), pos_of[i] = pos (coalesced).
__global__ void scatter_kernel(const int* __restrict__ ei, int E, int N,
                               int* __restrict__ cursor,
                               int* __restrict__ csr_src,
                               int* __restrict__ pos_of) {
  const int total = E + N;
  for (int i = blockIdx.x * blockDim.x + threadIdx.x; i < total;
       i += gridDim.x * blockDim.x) {
    int s, d;
    if (i < E) { s = ei[i]; d = ei[E + i]; } else { s = d = i - E; }
    const int pos = atomicAdd(&cursor[d], 1);
    csr_src[pos] = s;
    pos_of[i] = pos;
  }
}

// ---------------------------------------------------------------------------
// small helpers
// ---------------------------------------------------------------------------
__global__ void mmse_kernel(const float* __restrict__ score,
                            const float* __restrict__ W,
                            const float* __restrict__ b,
                            float* __restrict__ out, int D) {
  const int i = threadIdx.x;
  if (i < D) out[i] = score[0] * W[i] + b[i];
}

__global__ void wt_kernel(const float* __restrict__ Wl,
                          const float* __restrict__ Wr,
                          bf16* __restrict__ Wt, int K) {
  const int idx = blockIdx.x * blockDim.x + threadIdx.x;
  if (idx >= 256 * K) return;
  const int col = idx & 255;
  const int k = idx >> 8;
  const float v = (col < 128) ? Wl[k * 128 + col] : Wr[k * 128 + (col - 128)];
  Wt[(size_t)col * K + k] = (bf16)v;
}

// ---------------------------------------------------------------------------
// MFMA GEMM: [xl | xr] = A[M][K] @ Wt^T   (Wt is [256][K] bf16, col-major W)
// BM=128, BN=256, BK=32; 512 threads = 8 waves (2x4), 64x64 per wave.
// ---------------------------------------------------------------------------
template <bool AF32>
__global__ __launch_bounds__(512) void gemm_mfma(
    const void* __restrict__ Ap, const bf16* __restrict__ Wt,
    bf16* __restrict__ xl, bf16* __restrict__ xr, int M, int K) {
  __shared__ __align__(16) bf16 Alds[128 * 32];
  __shared__ __align__(16) bf16 Blds[256 * 32];

  const int tid = threadIdx.x;
  const int w = tid >> 6, lane = tid & 63;
  const int wr = w >> 2, wc = w & 3;
  const int row0 = blockIdx.x * 128;

  const int s_row = tid >> 2;
  const int s_k = (tid & 3) * 8;
  const int a_row = min(row0 + s_row, M - 1);
  bf16* a_dst = Alds + tid * 8;

  const int b_col0 = w * 32 + (lane >> 2);
  const bf16* b_src0 = Wt + (size_t)b_col0 * K + (lane & 3) * 8;
  const bf16* b_src1 = Wt + (size_t)(b_col0 + 16) * K + (lane & 3) * 8;
  bf16* b_dst0 = Blds + w * 1024 + lane * 8;
  bf16* b_dst1 = b_dst0 + 512;

  const int a_f0 = (wr * 64 + (lane & 15)) * 32 + (lane >> 4) * 8;
  const int b_f0 = (wc * 64 + (lane & 15)) * 32 + (lane >> 4) * 8;

  f32x4 acc[4][4] = {};

  for (int k0 = 0; k0 < K; k0 += 32) {
    bf16x8 av;
    if (AF32) {
      const float* A = (const float*)Ap;
      const float4 f0 = *(const float4*)&A[(size_t)a_row * K + k0 + s_k];
      const float4 f1 = *(const float4*)&A[(size_t)a_row * K + k0 + s_k + 4];
      av[0] = (bf16)f0.x; av[1] = (bf16)f0.y; av[2] = (bf16)f0.z; av[3] = (bf16)f0.w;
      av[4] = (bf16)f1.x; av[5] = (bf16)f1.y; av[6] = (bf16)f1.z; av[7] = (bf16)f1.w;
    } else {
      av = *(const bf16x8*)((const bf16*)Ap + (size_t)a_row * K + k0 + s_k);
    }
    __syncthreads();
    *(bf16x8*)a_dst = av;
    load_lds16(b_src0 + k0, b_dst0);
    load_lds16(b_src1 + k0, b_dst1);
    __syncthreads();

    bf16x8 af[4], bfr[4];
#pragma unroll
    for (int m = 0; m < 4; ++m) af[m] = *(const bf16x8*)(Alds + a_f0 + m * 512);
#pragma unroll
    for (int n = 0; n < 4; ++n) bfr[n] = *(const bf16x8*)(Blds + b_f0 + n * 512);
#pragma unroll
    for (int m = 0; m < 4; ++m)
#pragma unroll
      for (int n = 0; n < 4; ++n)
        acc[m][n] = __builtin_amdgcn_mfma_f32_16x16x32_bf16(af[m], bfr[n],
                                                            acc[m][n], 0, 0, 0);
  }

#pragma unroll
  for (int m = 0; m < 4; ++m) {
    const int rbase = row0 + wr * 64 + m * 16 + (lane >> 4) * 4;
#pragma unroll
    for (int n = 0; n < 4; ++n) {
      const int c = wc * 64 + n * 16 + (lane & 15);
      bf16* dst = (c < 128) ? xl : xr;
      const int cc = c & 127;
#pragma unroll
      for (int j = 0; j < 4; ++j) {
        const int r = rbase + j;
        if (r < M) dst[(size_t)r * 128 + cc] = (bf16)acc[m][n][j];
      }
    }
  }
}

// ---------------------------------------------------------------------------
// edge phase v7: v3's simple batched loop (best measured: 84us @ 68 VGPR),
// + coalesced e_ws (CSR order, no eid in hot loop) + fmaxf LeakyReLU.
// __launch_bounds__(256,4): VGPR cap 128 -> compiler's natural ~64-72, NO
// spill (round 9: cap 64 forced VGPR 32 -> 536 MB scratch traffic, 2.8x
// slower; occupancy is NOT worth spilling for here).
// 2 nodes per wave (32-lane halves), 4 dims per lane, 8-edge batches.
// ---------------------------------------------------------------------------
__global__ __launch_bounds__(256, 4) void gat_edge(
    const bf16* __restrict__ xl, const bf16* __restrict__ xr,
    const int* __restrict__ row_ptr, const int* __restrict__ csr_src,
    const float* __restrict__ att, const float* __restrict__ bias,
    const float* __restrict__ extra,
    bf16* __restrict__ out_b,   // layer 1: attn1 (bf16) or null
    float* __restrict__ out_f,  // layer 2: out_feat (fp32) or null
    float* __restrict__ e_ws, float* __restrict__ m_ws,
    float* __restrict__ den_ws, int N) {
  const int wave = threadIdx.x >> 6;
  const int lane = threadIdx.x & 63;
  const int l5 = lane & 31;
  const int half = lane >> 5;
  const int node_raw = blockIdx.x * 8 + wave * 2 + half;
  const bool vnode = node_raw < N;
  const int node = vnode ? node_raw : N - 1;

  const int d0 = l5 * 4;
  const float4 attv = *(const float4*)&att[d0];
  const uint2 ur = *(const uint2*)&xr[(size_t)node * 128 + d0];
  const float r0 = bf_lo(ur.x), r1 = bf_hi(ur.x);
  const float r2 = bf_lo(ur.y), r3 = bf_hi(ur.y);

  float m = -1e30f, den = 0.f;
  float a0 = 0.f, a1 = 0.f, a2 = 0.f, a3 = 0.f;

  const int beg = vnode ? row_ptr[node] : 0;
  const int end = vnode ? row_ptr[node + 1] : 0;
  const int nbat = (end - beg + 7) >> 3;
  const int nloop = max(nbat, __shfl_xor(nbat, 32));

  for (int t = 0; t < nloop; ++t) {
    const int idx = beg + t * 8;

    // 8 independent idx->gather chains; compiler interleaves them.
    uint2 u[8];
#pragma unroll
    for (int j = 0; j < 8; ++j) {
      const int k = idx + j;
      const int s = csr_src[(k < end) ? k : beg];  // ephemeral index reg
      u[j] = *(const uint2*)&xl[(size_t)s * 128 + d0];
    }

    float p[8];
#pragma unroll
    for (int j = 0; j < 8; ++j) {
      float h0 = bf_lo(u[j].x) + r0;
      float h1 = bf_hi(u[j].x) + r1;
      float h2 = bf_lo(u[j].y) + r2;
      float h3 = bf_hi(u[j].y) + r3;
      h0 = fmaxf(h0, 0.2f * h0);  // LeakyReLU: max(h, 0.2h)
      h1 = fmaxf(h1, 0.2f * h1);
      h2 = fmaxf(h2, 0.2f * h2);
      h3 = fmaxf(h3, 0.2f * h3);
      p[j] = fmaf(h0, attv.x, fmaf(h1, attv.y, fmaf(h2, attv.z, h3 * attv.w)));
    }

    // reduce within each 32-lane half (offsets preserve the half bit)
#pragma unroll
    for (int off = 16; off; off >>= 1) {
#pragma unroll
      for (int j = 0; j < 8; ++j) p[j] += __shfl_xor(p[j], off);
    }

#pragma unroll
    for (int j = 0; j < 8; ++j)
      if (idx + j >= end) p[j] = -1e30f;  // masked: weight 0

    if (e_ws != nullptr && l5 == 0) {
#pragma unroll
      for (int j = 0; j < 8; ++j)
        if (idx + j < end) e_ws[idx + j] = p[j];  // CSR order: coalesced
    }

    const float bm = fmaxf(fmaxf(fmaxf(p[0], p[1]), fmaxf(p[2], p[3])),
                           fmaxf(fmaxf(p[4], p[5]), fmaxf(p[6], p[7])));
    if (bm > m) {
      const float f = __expf(m - bm);  // 0 on first batch
      den *= f;
      a0 *= f; a1 *= f; a2 *= f; a3 *= f;
      m = bm;
    }
#pragma unroll
    for (int j = 0; j < 8; ++j) {
      const float wgt = __expf(p[j] - m);
      den += wgt;
      a0 = fmaf(wgt, bf_lo(u[j].x), a0);
      a1 = fmaf(wgt, bf_hi(u[j].x), a1);
      a2 = fmaf(wgt, bf_lo(u[j].y), a2);
      a3 = fmaf(wgt, bf_hi(u[j].y), a3);
    }
  }

  if (!vnode) return;

  const float inv = 1.f / den;
  const float4 bv = *(const float4*)&bias[d0];
  float o0 = fmaf(a0, inv, bv.x);
  float o1 = fmaf(a1, inv, bv.y);
  float o2 = fmaf(a2, inv, bv.z);
  float o3 = fmaf(a3, inv, bv.w);
  if (extra != nullptr) {
    const float4 ev = *(const float4*)&extra[d0];
    o0 += ev.x; o1 += ev.y; o2 += ev.z; o3 += ev.w;
  }
  if (out_b != nullptr) {
    uint2 pk;
    pk.x = (unsigned)bf16_bits(o0) | ((unsigned)bf16_bits(o1) << 16);
    pk.y = (unsigned)bf16_bits(o2) | ((unsigned)bf16_bits(o3) << 16);
    *(uint2*)&out_b[(size_t)node * 128 + d0] = pk;
  }
  if (out_f != nullptr) {
    float4 ov; ov.x = o0; ov.y = o1; ov.z = o2; ov.w = o3;
    *(float4*)&out_f[(size_t)node * 128 + d0] = ov;
  }
  if (m_ws != nullptr && l5 == 0) {
    m_ws[node] = m;
    den_ws[node] = den;
  }
}

// alpha[i] = exp(e[pos_of[i]] - m[dst]) / den[dst]  (original edge order)
__global__ void alpha_kernel(const float* __restrict__ e_ws,
                             const float* __restrict__ m_ws,
                             const float* __restrict__ den_ws,
                             const int* __restrict__ ei,
                             const int* __restrict__ pos_of, int E, int N,
                             float* __restrict__ out_alpha) {
  const int i = blockIdx.x * blockDim.x + threadIdx.x;
  if (i >= E + N) return;
  const int d = (i < E) ? ei[E + i] : (i - E);
  const int pos = pos_of[i];
  out_alpha[i] = __expf(e_ws[pos] - m_ws[d]) / den_ws[d];
}

// ---------------------------------------------------------------------------
extern "C" void kernel_launch(void* const* d_in, const int* in_sizes, int n_in,
                              void* d_out, int out_size, void* d_ws,
                              size_t ws_size, hipStream_t stream) {
  const float* x          = (const float*)d_in[0];
  const int*   ei         = (const int*)d_in[1];
  const float* mmse_score = (const float*)d_in[2];
  const float* W_l1       = (const float*)d_in[3];
  const float* W_r1       = (const float*)d_in[4];
  const float* att1       = (const float*)d_in[5];
  const float* bias1      = (const float*)d_in[6];
  const float* W_l2       = (const float*)d_in[7];
  const float* W_r2       = (const float*)d_in[8];
  const float* att2       = (const float*)d_in[9];
  const float* bias2      = (const float*)d_in[10];
  const float* mmse_W     = (const float*)d_in[11];
  const float* mmse_b     = (const float*)d_in[12];

  const int D  = in_sizes[5];      // 128
  const int T  = in_sizes[3] / D;  // 512
  const int N  = in_sizes[0] / T;  // 50000
  const int E  = in_sizes[1] / 2;  // 800000
  const int ET = E + N;

  char* wptr = (char*)d_ws;
  auto alloc = [&](size_t bytes) {
    char* p = wptr;
    wptr += (bytes + 255) & ~(size_t)255;
    return p;
  };
  bf16* xl      = (bf16*)alloc((size_t)N * 128 * 2);
  bf16* xr      = (bf16*)alloc((size_t)N * 128 * 2);
  bf16* attn1   = (bf16*)alloc((size_t)N * 128 * 2);
  bf16* Wt1     = (bf16*)alloc((size_t)256 * T * 2);
  bf16* Wt2     = (bf16*)alloc((size_t)256 * D * 2);
  float* e_ws   = (float*)alloc((size_t)ET * 4);
  float* m_ws   = (float*)alloc((size_t)N * 4);
  float* den_ws = (float*)alloc((size_t)N * 4);
  float* mmse_vec = (float*)alloc(512);
  int* counts  = (int*)alloc((size_t)N * 4);
  int* row_ptr = (int*)alloc((size_t)(N + 1) * 4);
  int* cursor  = (int*)alloc((size_t)N * 4);
  int* bsum    = (int*)alloc(256 * 4);
  int* csr_src = (int*)alloc((size_t)ET * 4);
  int* pos_of  = (int*)alloc((size_t)ET * 4);

  float* out_feat  = (float*)d_out;             // N*128
  float* out_alpha = out_feat + (size_t)N * D;  // ET

  // 1. CSR by dst (parallel scan)
  hipMemsetAsync(counts, 0, (size_t)N * 4, stream);
  hist_kernel<<<2048, 256, 0, stream>>>(ei, E, N, counts);
  scan_reduce<<<256, 256, 0, stream>>>(counts, bsum, N);
  scan_bsum<<<1, 256, 0, stream>>>(bsum, row_ptr, N);
  scan_write<<<256, 256, 0, stream>>>(counts, bsum, row_ptr, cursor, N);
  scatter_kernel<<<2048, 256, 0, stream>>>(ei, E, N, cursor, csr_src, pos_of);

  // 2. weight prep + mmse embedding
  wt_kernel<<<(256 * T + 255) / 256, 256, 0, stream>>>(W_l1, W_r1, Wt1, T);
  wt_kernel<<<(256 * D + 255) / 256, 256, 0, stream>>>(W_l2, W_r2, Wt2, D);
  mmse_kernel<<<1, 128, 0, stream>>>(mmse_score, mmse_W, mmse_b, mmse_vec, D);

  // 3. layer-1 GEMM (fp32 A, converts inline) -> xl/xr bf16
  const int gblocks = (N + 127) / 128;
  gemm_mfma<true><<<gblocks, 512, 0, stream>>>(x, Wt1, xl, xr, N, T);

  // 4. layer-1 edge phase -> attn1 bf16, logits (CSR order) for alpha
  gat_edge<<<(N + 7) / 8, 256, 0, stream>>>(xl, xr, row_ptr, csr_src, att1,
                                            bias1, nullptr, attn1, nullptr,
                                            e_ws, m_ws, den_ws, N);

  // 5. alpha in original edge order
  alpha_kernel<<<(ET + 255) / 256, 256, 0, stream>>>(e_ws, m_ws, den_ws, ei,
                                                     pos_of, E, N, out_alpha);

  // 6. layer-2 GEMM (bf16 A = attn1) -> xl/xr reused
  gemm_mfma<false><<<gblocks, 512, 0, stream>>>(attn1, Wt2, xl, xr, N, D);

  // 7. layer-2 edge phase -> out_feat fp32 (+ mmse embedding)
  gat_edge<<<(N + 7) / 8, 256, 0, stream>>>(xl, xr, row_ptr, csr_src, att2,
                                            bias2, mmse_vec, nullptr, out_feat,
                                            nullptr, nullptr, nullptr, N);
}